// Round 1
// baseline (3318.398 us; speedup 1.0000x reference)
//
#include <hip/hip_runtime.h>
#include <math.h>

#define NN 50000
#define TT 9
#define FD 128
#define HD 128

// ---------------------------------------------------------------------------
// Edge dtype detection: reference says int64 but JAX canonicalizes to int32
// unless x64 is enabled. For int64, values < 50000 => every high u32 word is 0.
// Writes word-stride (2 = int64, 1 = int32) to ws.
// ---------------------------------------------------------------------------
__global__ void k_detect(const unsigned int* __restrict__ e32, int nchk,
                         int* __restrict__ stride_out) {
  __shared__ unsigned int red[256];
  unsigned int acc = 0;
  for (int i = threadIdx.x; i < nchk; i += 256) acc |= e32[2 * i + 1];
  red[threadIdx.x] = acc;
  __syncthreads();
  for (int s = 128; s > 0; s >>= 1) {
    if ((int)threadIdx.x < s) red[threadIdx.x] |= red[threadIdx.x + s];
    __syncthreads();
  }
  if (threadIdx.x == 0) stride_out[0] = (red[0] == 0u) ? 2 : 1;
}

__global__ void k_count(const unsigned int* __restrict__ e32, int E,
                        const int* __restrict__ stridep, int* __restrict__ cnt) {
  int e = blockIdx.x * 256 + threadIdx.x;
  if (e >= E) return;
  int st = stridep[0];
  int d = (int)e32[(size_t)(E + e) * st];
  atomicAdd(&cnt[d], 1);
}

__global__ void k_dinv(const int* __restrict__ cnt, float* __restrict__ dinv, int N) {
  int n = blockIdx.x * 256 + threadIdx.x;
  if (n < N) dinv[n] = rsqrtf((float)(cnt[n] + 1));  // +1 self-loop, always > 0
}

// single-block exclusive scan of cnt[0..N) -> rowp[0..N]
__global__ void k_scan(const int* __restrict__ cnt, int* __restrict__ rowp, int N) {
  __shared__ int buf[1024];
  __shared__ int carry_s;
  if (threadIdx.x == 0) carry_s = 0;
  __syncthreads();
  for (int base = 0; base < N; base += 1024) {
    int i = base + threadIdx.x;
    int v = (i < N) ? cnt[i] : 0;
    buf[threadIdx.x] = v;
    __syncthreads();
    for (int off = 1; off < 1024; off <<= 1) {
      int t = ((int)threadIdx.x >= off) ? buf[threadIdx.x - off] : 0;
      __syncthreads();
      buf[threadIdx.x] += t;
      __syncthreads();
    }
    int incl = buf[threadIdx.x];
    int carry = carry_s;
    if (i < N) rowp[i] = carry + incl - v;
    __syncthreads();
    if (threadIdx.x == 1023) carry_s = carry + incl;
    __syncthreads();
  }
  if (threadIdx.x == 0) rowp[N] = carry_s;
}

__global__ void k_scatter(const unsigned int* __restrict__ e32, int E,
                          const int* __restrict__ stridep, const int* __restrict__ rowp,
                          int* __restrict__ fill, int* __restrict__ col) {
  int e = blockIdx.x * 256 + threadIdx.x;
  if (e >= E) return;
  int st = stridep[0];
  int s = (int)e32[(size_t)e * st];
  int d = (int)e32[(size_t)(E + e) * st];
  int pos = rowp[d] + atomicAdd(&fill[d], 1);
  col[pos] = s;
}

// ---------------------------------------------------------------------------
// aggx[n] = dinv[n] * ( sum_{e->n} dinv[src]*x[src]  +  dinv[n]*x[n] )
// one wave per node; lane holds 2 of 128 cols (float2 = 8B/lane, 512B/wave gather)
// ---------------------------------------------------------------------------
__global__ __launch_bounds__(256) void k_agg(const float* __restrict__ xt,
                                             const float* __restrict__ dinv,
                                             const int* __restrict__ rowp,
                                             const int* __restrict__ col,
                                             float* __restrict__ aggx) {
  int lane = threadIdx.x & 63;
  int n = blockIdx.x * 4 + (threadIdx.x >> 6);
  if (n >= NN) return;
  int c2 = lane * 2;
  float dn = dinv[n];
  float2 xv = *(const float2*)(xt + (size_t)n * FD + c2);
  float accx = dn * xv.x, accy = dn * xv.y;
  int beg = rowp[n], end = rowp[n + 1];
  for (int base = beg; base < end; base += 64) {
    int m = end - base;
    if (m > 64) m = 64;
    int sl = (lane < m) ? col[base + lane] : 0;
    for (int j = 0; j < m; ++j) {
      int s = __shfl(sl, j);
      float w = dinv[s];
      float2 g = *(const float2*)(xt + (size_t)s * FD + c2);
      accx = fmaf(w, g.x, accx);
      accy = fmaf(w, g.y, accy);
    }
  }
  float2 r;
  r.x = accx * dn;
  r.y = accy * dn;
  *(float2*)(aggx + (size_t)n * FD + c2) = r;
}

// ---------------------------------------------------------------------------
// emb = relu(aggx @ W_gcn + b_gcn).  128x128 tile, 256 thr, 8x8 micro, kc=32.
// ---------------------------------------------------------------------------
__global__ __launch_bounds__(256) void k_emb(const float* __restrict__ A,
                                             const float* __restrict__ W,
                                             const float* __restrict__ bias,
                                             float* __restrict__ out, int M) {
  __shared__ float At[32][128];  // [k][row]
  __shared__ float Bs[32][128];  // [k][col]
  int tid = threadIdx.x;
  int r0 = blockIdx.x * 128;
  int ty = tid >> 4, tx = tid & 15;
  float acc[8][8] = {};
  for (int chunk = 0; chunk < 4; ++chunk) {
    int kbase = chunk * 32;
    {  // stage A transposed
      int r = tid & 127, kh = tid >> 7;
      int grow = r0 + r;
#pragma unroll
      for (int u = 0; u < 4; ++u) {
        int kl = kh * 16 + u * 4;
        float4 v = make_float4(0.f, 0.f, 0.f, 0.f);
        if (grow < M) v = *(const float4*)(A + (size_t)grow * FD + kbase + kl);
        At[kl + 0][r] = v.x; At[kl + 1][r] = v.y;
        At[kl + 2][r] = v.z; At[kl + 3][r] = v.w;
      }
    }
    {  // stage B straight (W row-major [k][j])
#pragma unroll
      for (int u = 0; u < 4; ++u) {
        int f = tid + u * 256;
        int kl = f >> 5;
        int j = (f & 31) * 4;
        *(float4*)(&Bs[kl][j]) = *(const float4*)(W + (size_t)(kbase + kl) * 128 + j);
      }
    }
    __syncthreads();
#pragma unroll 8
    for (int k = 0; k < 32; ++k) {
      float a[8], b[8];
      *(float4*)(a)     = *(const float4*)(&At[k][ty * 8]);
      *(float4*)(a + 4) = *(const float4*)(&At[k][ty * 8 + 4]);
      *(float4*)(b)     = *(const float4*)(&Bs[k][tx * 8]);
      *(float4*)(b + 4) = *(const float4*)(&Bs[k][tx * 8 + 4]);
#pragma unroll
      for (int i = 0; i < 8; ++i)
#pragma unroll
        for (int q = 0; q < 8; ++q) acc[i][q] = fmaf(a[i], b[q], acc[i][q]);
    }
    __syncthreads();
  }
  float bv[8];
  *(float4*)(bv)     = *(const float4*)(bias + tx * 8);
  *(float4*)(bv + 4) = *(const float4*)(bias + tx * 8 + 4);
  for (int i = 0; i < 8; ++i) {
    int r = r0 + ty * 8 + i;
    if (r >= M) break;
    float o[8];
#pragma unroll
    for (int q = 0; q < 8; ++q) {
      float v = acc[i][q] + bv[q];
      o[q] = v > 0.f ? v : 0.f;
    }
    *(float4*)(out + (size_t)r * HD + tx * 8)     = *(float4*)(o);
    *(float4*)(out + (size_t)r * HD + tx * 8 + 4) = *(float4*)(o + 4);
  }
}

// ---------------------------------------------------------------------------
// Fused LSTM step: gates = emb@W_ih^T + h@W_hh^T + b  -> c,h update.
// Tile: 128 rows x (32 hidden x 4 gates). K=256 (emb k0..127, h k128..255).
// LDS col index cc = j_local*4 + gate, so each thread's 8 cols = 2 hidden
// units with all 4 gates -> epilogue is self-contained.
// ---------------------------------------------------------------------------
__global__ __launch_bounds__(256) void k_lstm(const float* __restrict__ emb,
                                              const float* __restrict__ hprev,
                                              const float* __restrict__ Wih,
                                              const float* __restrict__ Whh,
                                              const float* __restrict__ bih,
                                              const float* __restrict__ bhh,
                                              float* __restrict__ hnext,
                                              float* __restrict__ cbuf, int M) {
  __shared__ float At[32][128];
  __shared__ float Bs[32][128];
  int tid = threadIdx.x;
  int r0 = blockIdx.x * 128;
  int j0 = blockIdx.y * 32;
  int ty = tid >> 4, tx = tid & 15;
  float acc[8][8] = {};
  for (int chunk = 0; chunk < 8; ++chunk) {
    const float* Asrc = (chunk < 4) ? emb : hprev;
    const float* Wsrc = (chunk < 4) ? Wih : Whh;
    int kbase = (chunk & 3) * 32;
    {  // stage A transposed
      int r = tid & 127, kh = tid >> 7;
      int grow = r0 + r;
#pragma unroll
      for (int u = 0; u < 4; ++u) {
        int kl = kh * 16 + u * 4;
        float4 v = make_float4(0.f, 0.f, 0.f, 0.f);
        if (grow < M) v = *(const float4*)(Asrc + (size_t)grow * HD + kbase + kl);
        At[kl + 0][r] = v.x; At[kl + 1][r] = v.y;
        At[kl + 2][r] = v.z; At[kl + 3][r] = v.w;
      }
    }
    {  // stage B: Bs[kk][jl*4+g] = Wsrc[g*128 + j0 + jl][kbase+kk]
      int cc = tid & 127, kh = tid >> 7;
      int jl = cc >> 2, g = cc & 3;
      const float* wrow = Wsrc + (size_t)(g * 128 + j0 + jl) * 128 + kbase;
#pragma unroll
      for (int u = 0; u < 4; ++u) {
        int kl = kh * 16 + u * 4;
        float4 v = *(const float4*)(wrow + kl);
        Bs[kl + 0][cc] = v.x; Bs[kl + 1][cc] = v.y;
        Bs[kl + 2][cc] = v.z; Bs[kl + 3][cc] = v.w;
      }
    }
    __syncthreads();
#pragma unroll 8
    for (int k = 0; k < 32; ++k) {
      float a[8], b[8];
      *(float4*)(a)     = *(const float4*)(&At[k][ty * 8]);
      *(float4*)(a + 4) = *(const float4*)(&At[k][ty * 8 + 4]);
      *(float4*)(b)     = *(const float4*)(&Bs[k][tx * 8]);
      *(float4*)(b + 4) = *(const float4*)(&Bs[k][tx * 8 + 4]);
#pragma unroll
      for (int i = 0; i < 8; ++i)
#pragma unroll
        for (int q = 0; q < 8; ++q) acc[i][q] = fmaf(a[i], b[q], acc[i][q]);
    }
    __syncthreads();
  }
  // epilogue: col q -> gate g = q&3, hidden jl = 2*tx + (q>>2)
  float bsum[8];
#pragma unroll
  for (int q = 0; q < 8; ++q) {
    int g = q & 3, jl = tx * 2 + (q >> 2);
    int idx = g * 128 + j0 + jl;
    bsum[q] = bih[idx] + bhh[idx];
  }
  for (int i = 0; i < 8; ++i) {
    int n = r0 + ty * 8 + i;
    if (n >= M) break;
    size_t off = (size_t)n * HD + j0 + tx * 2;
    float2 cold = *(const float2*)(cbuf + off);
    float2 cnew, hnew;
    {
      float gi = acc[i][0] + bsum[0], gf = acc[i][1] + bsum[1];
      float gg = acc[i][2] + bsum[2], go = acc[i][3] + bsum[3];
      float ig = 1.f / (1.f + expf(-gi));
      float fg = 1.f / (1.f + expf(-gf));
      float og = 1.f / (1.f + expf(-go));
      float gt = tanhf(gg);
      cnew.x = fg * cold.x + ig * gt;
      hnew.x = og * tanhf(cnew.x);
    }
    {
      float gi = acc[i][4] + bsum[4], gf = acc[i][5] + bsum[5];
      float gg = acc[i][6] + bsum[6], go = acc[i][7] + bsum[7];
      float ig = 1.f / (1.f + expf(-gi));
      float fg = 1.f / (1.f + expf(-gf));
      float og = 1.f / (1.f + expf(-go));
      float gt = tanhf(gg);
      cnew.y = fg * cold.y + ig * gt;
      hnew.y = og * tanhf(cnew.y);
    }
    *(float2*)(cbuf + off) = cnew;
    *(float2*)(hnext + off) = hnew;
  }
}

// out[n*T + t] = dot(h[n], W_fc) + b_fc ; one wave per node
__global__ __launch_bounds__(256) void k_out(const float* __restrict__ h,
                                             const float* __restrict__ Wfc,
                                             const float* __restrict__ bfc,
                                             float* __restrict__ out, int t, int M) {
  int lane = threadIdx.x & 63;
  int n = blockIdx.x * 4 + (threadIdx.x >> 6);
  if (n >= M) return;
  float2 hv = *(const float2*)(h + (size_t)n * HD + lane * 2);
  float2 wv = *(const float2*)(Wfc + lane * 2);
  float s = fmaf(hv.x, wv.x, hv.y * wv.y);
#pragma unroll
  for (int off = 32; off > 0; off >>= 1) s += __shfl_xor(s, off);
  if (lane == 0) out[(size_t)n * TT + t] = s + bfc[0];
}

// ---------------------------------------------------------------------------
static inline size_t alignup(size_t x) { return (x + 511) & ~(size_t)511; }

extern "C" void kernel_launch(void* const* d_in, const int* in_sizes, int n_in,
                              void* d_out, int out_size, void* d_ws, size_t ws_size,
                              hipStream_t stream) {
  const float* x_seq = (const float*)d_in[0];
  const unsigned int* e32 = (const unsigned int*)d_in[1];
  const float* W_gcn = (const float*)d_in[2];
  const float* b_gcn = (const float*)d_in[3];
  const float* W_ih = (const float*)d_in[4];
  const float* W_hh = (const float*)d_in[5];
  const float* b_ih = (const float*)d_in[6];
  const float* b_hh = (const float*)d_in[7];
  const float* W_fc = (const float*)d_in[8];
  const float* b_fc = (const float*)d_in[9];
  float* out = (float*)d_out;

  const int N = NN;
  const int E = in_sizes[1] / 2;

  char* p = (char*)d_ws;
  int* stridep = (int*)p;            p += 512;
  int* cnt     = (int*)p;            p += alignup((size_t)N * 4);
  int* rowp    = (int*)p;            p += alignup((size_t)(N + 1) * 4);
  int* fill    = (int*)p;            p += alignup((size_t)N * 4);
  int* col     = (int*)p;            p += alignup((size_t)E * 4);
  float* dinv  = (float*)p;          p += alignup((size_t)N * 4);
  float* aggx  = (float*)p;          p += alignup((size_t)N * FD * 4);
  float* emb   = (float*)p;          p += alignup((size_t)N * HD * 4);
  float* h0    = (float*)p;          p += alignup((size_t)N * HD * 4);
  float* h1    = (float*)p;          p += alignup((size_t)N * HD * 4);
  float* cbuf  = (float*)p;          p += alignup((size_t)N * HD * 4);

  hipMemsetAsync(cnt, 0, (size_t)N * 4, stream);
  hipMemsetAsync(fill, 0, (size_t)N * 4, stream);
  hipMemsetAsync(h0, 0, (size_t)N * HD * 4, stream);
  hipMemsetAsync(cbuf, 0, (size_t)N * HD * 4, stream);

  int nchk = E < 8192 ? E : 8192;
  k_detect<<<1, 256, 0, stream>>>(e32, nchk, stridep);
  k_count<<<(E + 255) / 256, 256, 0, stream>>>(e32, E, stridep, cnt);
  k_dinv<<<(N + 255) / 256, 256, 0, stream>>>(cnt, dinv, N);
  k_scan<<<1, 1024, 0, stream>>>(cnt, rowp, N);
  k_scatter<<<(E + 255) / 256, 256, 0, stream>>>(e32, E, stridep, rowp, fill, col);

  float* hb[2] = {h0, h1};
  const int mblocks = (N + 127) / 128;
  for (int t = 0; t < TT; ++t) {
    const float* xt = x_seq + (size_t)t * N * FD;
    k_agg<<<(N + 3) / 4, 256, 0, stream>>>(xt, dinv, rowp, col, aggx);
    k_emb<<<mblocks, 256, 0, stream>>>(aggx, W_gcn, b_gcn, emb, N);
    float* hp = hb[t & 1];
    float* hn = hb[(t + 1) & 1];
    k_lstm<<<dim3(mblocks, 4), 256, 0, stream>>>(emb, hp, W_ih, W_hh, b_ih, b_hh,
                                                 hn, cbuf, N);
    k_out<<<(N + 3) / 4, 256, 0, stream>>>(hn, W_fc, b_fc, out, t, N);
  }
}

// Round 2
// 2638.649 us; speedup vs baseline: 1.2576x; 1.2576x over previous
//
#include <hip/hip_runtime.h>
#include <math.h>

#define NN 50000
#define TT 9
#define FD 128
#define HD 128

using short8 = __attribute__((ext_vector_type(8))) short;
using f32x4  = __attribute__((ext_vector_type(4))) float;

__device__ inline unsigned short f2bf(float x) {
  unsigned int u = __float_as_uint(x);
  unsigned int r = (u + 0x7fffu + ((u >> 16) & 1u)) >> 16;
  return (unsigned short)r;
}
__device__ inline float bf2f(unsigned short h) {
  return __uint_as_float(((unsigned int)h) << 16);
}
__device__ inline void split2(float x, unsigned short& h, unsigned short& l) {
  h = f2bf(x);
  l = f2bf(x - bf2f(h));
}
__device__ inline float fast_sigmoid(float x) {
  x = fminf(fmaxf(x, -30.f), 30.f);
  return 1.f / (1.f + __expf(-x));
}
__device__ inline float fast_tanh(float x) {
  x = fminf(fmaxf(x, -15.f), 15.f);
  float e = __expf(2.f * x);
  return (e - 1.f) / (e + 1.f);
}

// ---------------------------------------------------------------------------
// CSR build (same as round 1)
// ---------------------------------------------------------------------------
__global__ void k_detect(const unsigned int* __restrict__ e32, int nchk,
                         int* __restrict__ stride_out) {
  __shared__ unsigned int red[256];
  unsigned int acc = 0;
  for (int i = threadIdx.x; i < nchk; i += 256) acc |= e32[2 * i + 1];
  red[threadIdx.x] = acc;
  __syncthreads();
  for (int s = 128; s > 0; s >>= 1) {
    if ((int)threadIdx.x < s) red[threadIdx.x] |= red[threadIdx.x + s];
    __syncthreads();
  }
  if (threadIdx.x == 0) stride_out[0] = (red[0] == 0u) ? 2 : 1;
}

__global__ void k_count(const unsigned int* __restrict__ e32, int E,
                        const int* __restrict__ stridep, int* __restrict__ cnt) {
  int e = blockIdx.x * 256 + threadIdx.x;
  if (e >= E) return;
  int st = stridep[0];
  int d = (int)e32[(size_t)(E + e) * st];
  atomicAdd(&cnt[d], 1);
}

__global__ void k_dinv(const int* __restrict__ cnt, float* __restrict__ dinv, int N) {
  int n = blockIdx.x * 256 + threadIdx.x;
  if (n < N) dinv[n] = rsqrtf((float)(cnt[n] + 1));
}

__global__ void k_scan(const int* __restrict__ cnt, int* __restrict__ rowp, int N) {
  __shared__ int buf[1024];
  __shared__ int carry_s;
  if (threadIdx.x == 0) carry_s = 0;
  __syncthreads();
  for (int base = 0; base < N; base += 1024) {
    int i = base + threadIdx.x;
    int v = (i < N) ? cnt[i] : 0;
    buf[threadIdx.x] = v;
    __syncthreads();
    for (int off = 1; off < 1024; off <<= 1) {
      int t = ((int)threadIdx.x >= off) ? buf[threadIdx.x - off] : 0;
      __syncthreads();
      buf[threadIdx.x] += t;
      __syncthreads();
    }
    int incl = buf[threadIdx.x];
    int carry = carry_s;
    if (i < N) rowp[i] = carry + incl - v;
    __syncthreads();
    if (threadIdx.x == 1023) carry_s = carry + incl;
    __syncthreads();
  }
  if (threadIdx.x == 0) rowp[N] = carry_s;
}

__global__ void k_scatter(const unsigned int* __restrict__ e32, int E,
                          const int* __restrict__ stridep, const int* __restrict__ rowp,
                          int* __restrict__ fill, int* __restrict__ col) {
  int e = blockIdx.x * 256 + threadIdx.x;
  if (e >= E) return;
  int st = stridep[0];
  int s = (int)e32[(size_t)e * st];
  int d = (int)e32[(size_t)(E + e) * st];
  int pos = rowp[d] + atomicAdd(&fill[d], 1);
  col[pos] = s;
}

// ---------------------------------------------------------------------------
// Weight packing (once per launch)
// wpk row ri = 4*jl + g  <-  W_* row g*128+jl ; cols [0..127]=W_ih, [128..255]=W_hh
// ---------------------------------------------------------------------------
__global__ void k_packw(const float* __restrict__ Wih, const float* __restrict__ Whh,
                        const float* __restrict__ bih, const float* __restrict__ bhh,
                        unsigned short* __restrict__ Wh_, unsigned short* __restrict__ Wl_,
                        float* __restrict__ bsum) {
  int r = blockIdx.x;   // original row 0..511
  int k = threadIdx.x;  // 0..127
  int g = r >> 7, jl = r & 127;
  int ri = jl * 4 + g;
  unsigned short h, l;
  split2(Wih[(size_t)r * 128 + k], h, l);
  Wh_[(size_t)ri * 256 + k] = h;
  Wl_[(size_t)ri * 256 + k] = l;
  split2(Whh[(size_t)r * 128 + k], h, l);
  Wh_[(size_t)ri * 256 + 128 + k] = h;
  Wl_[(size_t)ri * 256 + 128 + k] = l;
  if (k == 0) bsum[ri] = bih[r] + bhh[r];
}

// wgt[h][k] = W_gcn[k][h] split
__global__ void k_packg(const float* __restrict__ Wg, unsigned short* __restrict__ Wh_,
                        unsigned short* __restrict__ Wl_) {
  int h = blockIdx.x, k = threadIdx.x;
  unsigned short hh, ll;
  split2(Wg[(size_t)k * 128 + h], hh, ll);
  Wh_[(size_t)h * 128 + k] = hh;
  Wl_[(size_t)h * 128 + k] = ll;
}

// ---------------------------------------------------------------------------
// aggregation: writes split bf16 hi/lo
// ---------------------------------------------------------------------------
__global__ __launch_bounds__(256) void k_agg(const float* __restrict__ xt,
                                             const float* __restrict__ dinv,
                                             const int* __restrict__ rowp,
                                             const int* __restrict__ col,
                                             unsigned short* __restrict__ aggh,
                                             unsigned short* __restrict__ aggl) {
  int lane = threadIdx.x & 63;
  int n = blockIdx.x * 4 + (threadIdx.x >> 6);
  if (n >= NN) return;
  int c2 = lane * 2;
  float dn = dinv[n];
  float2 xv = *(const float2*)(xt + (size_t)n * FD + c2);
  float accx = dn * xv.x, accy = dn * xv.y;
  int beg = rowp[n], end = rowp[n + 1];
  for (int base = beg; base < end; base += 64) {
    int m = end - base;
    if (m > 64) m = 64;
    int sl = (lane < m) ? col[base + lane] : 0;
    for (int j = 0; j < m; ++j) {
      int s = __shfl(sl, j);
      float w = dinv[s];
      float2 g = *(const float2*)(xt + (size_t)s * FD + c2);
      accx = fmaf(w, g.x, accx);
      accy = fmaf(w, g.y, accy);
    }
  }
  unsigned short hx, lx, hy, ly;
  split2(accx * dn, hx, lx);
  split2(accy * dn, hy, ly);
  ushort2 vh, vl;
  vh.x = hx; vh.y = hy;
  vl.x = lx; vl.y = ly;
  *(ushort2*)(aggh + (size_t)n * FD + c2) = vh;
  *(ushort2*)(aggl + (size_t)n * FD + c2) = vl;
}

// ---------------------------------------------------------------------------
// emb = relu(aggx @ W_gcn + b_gcn), split-bf16 MFMA.
// C[node][hid]: A-frag = aggx rows (k contiguous), B-frag = wgt rows (k contiguous).
// BM=128 nodes/block (wave: 2 rowtiles), 8 coltiles, K=128 (4 ksteps).
// ---------------------------------------------------------------------------
__global__ __launch_bounds__(256, 2) void k_embm(
    const unsigned short* __restrict__ Ah_, const unsigned short* __restrict__ Al_,
    const unsigned short* __restrict__ Wh_, const unsigned short* __restrict__ Wl_,
    const float* __restrict__ bg, unsigned short* __restrict__ Eh,
    unsigned short* __restrict__ El) {
  __shared__ unsigned int lds[128 * 128];  // 64 KiB pack buffer
  int tid = threadIdx.x;
  int w = tid >> 6, lane = tid & 63, q = lane >> 4, c = lane & 15;
  int n0 = blockIdx.x * 128;
  f32x4 acc[2][8] = {};
  for (int ks = 0; ks < 4; ++ks) {
    int kk = ks * 32 + q * 8;
    short8 bh[8], bl[8];
#pragma unroll
    for (int ct = 0; ct < 8; ++ct) {
      int hid = ct * 16 + c;
      bh[ct] = *(const short8*)(Wh_ + (size_t)hid * 128 + kk);
      bl[ct] = *(const short8*)(Wl_ + (size_t)hid * 128 + kk);
    }
#pragma unroll
    for (int rt = 0; rt < 2; ++rt) {
      int node = n0 + w * 32 + rt * 16 + c;
      short8 ah = {0, 0, 0, 0, 0, 0, 0, 0};
      short8 al = {0, 0, 0, 0, 0, 0, 0, 0};
      if (node < NN) {
        ah = *(const short8*)(Ah_ + (size_t)node * 128 + kk);
        al = *(const short8*)(Al_ + (size_t)node * 128 + kk);
      }
#pragma unroll
      for (int ct = 0; ct < 8; ++ct) {
        acc[rt][ct] = __builtin_amdgcn_mfma_f32_16x16x32_bf16(ah, bh[ct], acc[rt][ct], 0, 0, 0);
        acc[rt][ct] = __builtin_amdgcn_mfma_f32_16x16x32_bf16(ah, bl[ct], acc[rt][ct], 0, 0, 0);
        acc[rt][ct] = __builtin_amdgcn_mfma_f32_16x16x32_bf16(al, bh[ct], acc[rt][ct], 0, 0, 0);
      }
    }
  }
  // epilogue: bias + relu + split, pack into LDS [node_local][hid]
#pragma unroll
  for (int rt = 0; rt < 2; ++rt) {
#pragma unroll
    for (int ct = 0; ct < 8; ++ct) {
      float bv = bg[ct * 16 + c];
#pragma unroll
      for (int j = 0; j < 4; ++j) {
        int nl = w * 32 + rt * 16 + q * 4 + j;
        float v = acc[rt][ct][j] + bv;
        v = v > 0.f ? v : 0.f;
        unsigned short hh, hl;
        split2(v, hh, hl);
        lds[nl * 128 + ct * 16 + c] = ((unsigned int)hh << 16) | hl;
      }
    }
  }
  __syncthreads();
  // coalesced writeback: 128 rows x 16 chunks of 8
#pragma unroll
  for (int i = 0; i < 8; ++i) {
    int cid = i * 256 + tid;
    int row = cid >> 4, col8 = (cid & 15) * 8;
    int node = n0 + row;
    if (node >= NN) continue;
    short8 vh, vl;
#pragma unroll
    for (int u = 0; u < 8; ++u) {
      unsigned int v = lds[row * 128 + col8 + u];
      vh[u] = (short)(v >> 16);
      vl[u] = (short)(v & 0xffffu);
    }
    *(short8*)(Eh + (size_t)node * 128 + col8) = vh;
    *(short8*)(El + (size_t)node * 128 + col8) = vl;
  }
}

// ---------------------------------------------------------------------------
// Fused LSTM step via MFMA: gates^T[512 x 64nodes] = Wpk[512x256] @ X^T.
// Wave w owns gate-rows w*128..w*128+127 (hidden w*32..w*32+31, all 4 gates).
// acc[rt][ct][j]: j = gate (i,f,g,o), hidden jl = w*32+rt*4+q, node = n0+ct*16+c.
// Epilogue: gates->c,h (cT[hid][node] fp32), h split->LDS transpose->bf16 hi/lo,
// fused W_fc dot -> out.
// ---------------------------------------------------------------------------
__global__ __launch_bounds__(256, 2) void k_lstmm(
    const unsigned short* __restrict__ Eh, const unsigned short* __restrict__ El,
    const unsigned short* __restrict__ Hh, const unsigned short* __restrict__ Hl,
    const unsigned short* __restrict__ Wh_, const unsigned short* __restrict__ Wl_,
    const float* __restrict__ bsum, const float* __restrict__ Wfc,
    const float* __restrict__ bfc, unsigned short* __restrict__ Hh_n,
    unsigned short* __restrict__ Hl_n, float* __restrict__ cT,
    float* __restrict__ out, int tstep) {
  __shared__ unsigned int ldsH[64 * 129];
  __shared__ float obuf[4][64];
  int tid = threadIdx.x;
  int w = tid >> 6, lane = tid & 63, q = lane >> 4, c = lane & 15;
  int n0 = blockIdx.x * 64;
  f32x4 acc[8][4] = {};
  const short8 zz = {0, 0, 0, 0, 0, 0, 0, 0};
  for (int ks = 0; ks < 8; ++ks) {
    const unsigned short* sh = (ks < 4) ? Eh : Hh;
    const unsigned short* sl = (ks < 4) ? El : Hl;
    int kk = (ks & 3) * 32 + q * 8;
    short8 bh[4], bl[4];
#pragma unroll
    for (int ct = 0; ct < 4; ++ct) {
      int node = n0 + ct * 16 + c;
      if (node < NN) {
        bh[ct] = *(const short8*)(sh + (size_t)node * 128 + kk);
        bl[ct] = *(const short8*)(sl + (size_t)node * 128 + kk);
      } else {
        bh[ct] = zz;
        bl[ct] = zz;
      }
    }
    int ka = ks * 32 + q * 8;
#pragma unroll
    for (int rt = 0; rt < 8; ++rt) {
      int row = w * 128 + rt * 16 + c;
      short8 ah = *(const short8*)(Wh_ + (size_t)row * 256 + ka);
      short8 al = *(const short8*)(Wl_ + (size_t)row * 256 + ka);
#pragma unroll
      for (int ct = 0; ct < 4; ++ct) {
        acc[rt][ct] = __builtin_amdgcn_mfma_f32_16x16x32_bf16(ah, bh[ct], acc[rt][ct], 0, 0, 0);
        acc[rt][ct] = __builtin_amdgcn_mfma_f32_16x16x32_bf16(ah, bl[ct], acc[rt][ct], 0, 0, 0);
        acc[rt][ct] = __builtin_amdgcn_mfma_f32_16x16x32_bf16(al, bh[ct], acc[rt][ct], 0, 0, 0);
      }
    }
  }
  // epilogue
  float op[4] = {0.f, 0.f, 0.f, 0.f};
#pragma unroll
  for (int rt = 0; rt < 8; ++rt) {
    int jl = w * 32 + rt * 4 + q;
    float4 bs = *(const float4*)(bsum + 4 * jl);
    float wf = Wfc[jl];
#pragma unroll
    for (int ct = 0; ct < 4; ++ct) {
      int nl = ct * 16 + c;
      int node = n0 + nl;
      bool ok = node < NN;
      float gi = acc[rt][ct][0] + bs.x;
      float gf = acc[rt][ct][1] + bs.y;
      float gg = acc[rt][ct][2] + bs.z;
      float go = acc[rt][ct][3] + bs.w;
      float ig = fast_sigmoid(gi), fg = fast_sigmoid(gf), og = fast_sigmoid(go);
      float gt = fast_tanh(gg);
      size_t coff = (size_t)jl * NN + node;
      float cold = ok ? cT[coff] : 0.f;
      float cn = fg * cold + ig * gt;
      float hn = og * fast_tanh(cn);
      if (ok) cT[coff] = cn;
      op[ct] += hn * wf;
      unsigned short hh, hl;
      split2(hn, hh, hl);
      ldsH[nl * 129 + jl] = ((unsigned int)hh << 16) | hl;
    }
  }
#pragma unroll
  for (int ct = 0; ct < 4; ++ct) {
    op[ct] += __shfl_xor(op[ct], 16);
    op[ct] += __shfl_xor(op[ct], 32);
  }
  if (q == 0) {
#pragma unroll
    for (int ct = 0; ct < 4; ++ct) obuf[w][ct * 16 + c] = op[ct];
  }
  __syncthreads();
  // h writeback: 64 rows x 16 chunks of 8 -> 4 chunks/thread
#pragma unroll
  for (int i = 0; i < 4; ++i) {
    int cid = i * 256 + tid;
    int row = cid >> 4, col8 = (cid & 15) * 8;
    int node = n0 + row;
    if (node < NN) {
      short8 vh, vl;
#pragma unroll
      for (int u = 0; u < 8; ++u) {
        unsigned int v = ldsH[row * 129 + col8 + u];
        vh[u] = (short)(v >> 16);
        vl[u] = (short)(v & 0xffffu);
      }
      *(short8*)(Hh_n + (size_t)node * 128 + col8) = vh;
      *(short8*)(Hl_n + (size_t)node * 128 + col8) = vl;
    }
  }
  if (tid < 64) {
    int node = n0 + tid;
    if (node < NN) {
      float v = obuf[0][tid] + obuf[1][tid] + obuf[2][tid] + obuf[3][tid] + bfc[0];
      out[(size_t)node * TT + tstep] = v;
    }
  }
}

// ---------------------------------------------------------------------------
static inline size_t alignup(size_t x) { return (x + 511) & ~(size_t)511; }

extern "C" void kernel_launch(void* const* d_in, const int* in_sizes, int n_in,
                              void* d_out, int out_size, void* d_ws, size_t ws_size,
                              hipStream_t stream) {
  const float* x_seq = (const float*)d_in[0];
  const unsigned int* e32 = (const unsigned int*)d_in[1];
  const float* W_gcn = (const float*)d_in[2];
  const float* b_gcn = (const float*)d_in[3];
  const float* W_ih = (const float*)d_in[4];
  const float* W_hh = (const float*)d_in[5];
  const float* b_ih = (const float*)d_in[6];
  const float* b_hh = (const float*)d_in[7];
  const float* W_fc = (const float*)d_in[8];
  const float* b_fc = (const float*)d_in[9];
  float* out = (float*)d_out;

  const int N = NN;
  const int E = in_sizes[1] / 2;

  char* p = (char*)d_ws;
  int* stridep = (int*)p;              p += 512;
  int* cnt = (int*)p;                  p += alignup((size_t)N * 4);  // aliased as fill
  int* rowp = (int*)p;                 p += alignup((size_t)(N + 1) * 4);
  int* col = (int*)p;                  p += alignup((size_t)E * 4);
  float* dinv = (float*)p;             p += alignup((size_t)N * 4);
  unsigned short* aggh = (unsigned short*)p;  p += alignup((size_t)N * FD * 2);
  unsigned short* aggl = (unsigned short*)p;  p += alignup((size_t)N * FD * 2);
  unsigned short* embh = (unsigned short*)p;  p += alignup((size_t)N * HD * 2);
  unsigned short* embl = (unsigned short*)p;  p += alignup((size_t)N * HD * 2);
  unsigned short* h0h = (unsigned short*)p;   p += alignup((size_t)N * HD * 2);
  unsigned short* h0l = (unsigned short*)p;   p += alignup((size_t)N * HD * 2);
  unsigned short* h1h = (unsigned short*)p;   p += alignup((size_t)N * HD * 2);
  unsigned short* h1l = (unsigned short*)p;   p += alignup((size_t)N * HD * 2);
  float* cT = (float*)p;               p += alignup((size_t)HD * N * 4);
  unsigned short* wpkh = (unsigned short*)p;  p += alignup((size_t)512 * 256 * 2);
  unsigned short* wpkl = (unsigned short*)p;  p += alignup((size_t)512 * 256 * 2);
  unsigned short* wgth = (unsigned short*)p;  p += alignup((size_t)128 * 128 * 2);
  unsigned short* wgtl = (unsigned short*)p;  p += alignup((size_t)128 * 128 * 2);
  float* bsum = (float*)p;             p += alignup((size_t)512 * 4);

  hipMemsetAsync(cnt, 0, (size_t)N * 4, stream);
  hipMemsetAsync(h0h, 0, (size_t)N * HD * 2, stream);
  hipMemsetAsync(h0l, 0, (size_t)N * HD * 2, stream);
  hipMemsetAsync(cT, 0, (size_t)HD * N * 4, stream);

  int nchk = E < 8192 ? E : 8192;
  k_detect<<<1, 256, 0, stream>>>(e32, nchk, stridep);
  k_count<<<(E + 255) / 256, 256, 0, stream>>>(e32, E, stridep, cnt);
  k_dinv<<<(N + 255) / 256, 256, 0, stream>>>(cnt, dinv, N);
  k_scan<<<1, 1024, 0, stream>>>(cnt, rowp, N);
  hipMemsetAsync(cnt, 0, (size_t)N * 4, stream);  // reuse cnt as fill
  k_scatter<<<(E + 255) / 256, 256, 0, stream>>>(e32, E, stridep, rowp, cnt, col);
  k_packw<<<512, 128, 0, stream>>>(W_ih, W_hh, b_ih, b_hh, wpkh, wpkl, bsum);
  k_packg<<<128, 128, 0, stream>>>(W_gcn, wgth, wgtl);

  unsigned short* hbh[2] = {h0h, h1h};
  unsigned short* hbl[2] = {h0l, h1l};
  for (int t = 0; t < TT; ++t) {
    const float* xt = x_seq + (size_t)t * N * FD;
    k_agg<<<(N + 3) / 4, 256, 0, stream>>>(xt, dinv, rowp, col, aggh, aggl);
    k_embm<<<(N + 127) / 128, 256, 0, stream>>>(aggh, aggl, wgth, wgtl, b_gcn, embh, embl);
    k_lstmm<<<(N + 63) / 64, 256, 0, stream>>>(
        embh, embl, hbh[t & 1], hbl[t & 1], wpkh, wpkl, bsum, W_fc, b_fc,
        hbh[(t + 1) & 1], hbl[(t + 1) & 1], cT, out, t);
  }
}